// Round 10
// baseline (8383.833 us; speedup 1.0000x reference)
//
#include <hip/hip_runtime.h>
#include <stdint.h>
#include <stddef.h>

#define TT   128
#define BB   1024
#define INN  75
#define HH   128
#define KXP  96
#define OUTN 256
#define DECN 9600
#define EPSB 1e-5f
#define NBAR (2 * (TT + 1))

typedef short v8s __attribute__((ext_vector_type(8)));   // 8 bf16 (4 VGPR) MFMA frag
typedef float v4f __attribute__((ext_vector_type(4)));   // 4 fp32 acc frag
typedef unsigned short ush;
typedef unsigned int   u32;
typedef unsigned long long u64;

// ---- static device workspace (fully rewritten every launch) ----
__device__ __align__(256) ush g_xpad[(size_t)TT * BB * KXP];   // x padded to K=96, [t][b][k] bf16
__device__ __align__(256) u64 g_G1[(size_t)TT * 32 * BB * 4];  // BN(x@Wih0)+b0, [t][g][row][16 bf16]
__device__ __align__(256) u64 g_h0s[(size_t)TT * BB * 32];     // h0 stream [t][row][128 bf16] as u64
__device__ __align__(256) u64 g_h1s[(size_t)TT * BB * 32];     // h1 stream
__device__ __align__(256) u64 g_Pu[(size_t)3 * 32 * 1024 * 8]; // P[st][c][row][16 f32] as u64 pairs (6 MB)
__device__ __align__(256) u64 g_pstu[32 * 3 * 16 * 8];         // partial stats [c][st][cb][r8] {S,Q} u64
__device__ __align__(256) u32 g_barg[NBAR * 8];                // barrier group counters
__device__ __align__(256) u32 g_barr[NBAR];                    // barrier root counters
// weights [m][k] bf16, m permuted: origcol(m) = (m&3)*128 + (m>>4)*4 + ((m>>2)&3)
__device__ __align__(256) ush g_wtih0[512 * KXP];
__device__ __align__(256) ush g_wthh0[512 * HH];
__device__ __align__(256) ush g_wtih1[512 * HH];
__device__ __align__(256) ush g_wthh1[512 * HH];
__device__ __align__(256) ush g_fcwt[OUTN * HH];               // fc_w^T [col][k]
__device__ __align__(256) ush g_decwt[(size_t)DECN * OUTN];    // dec_w^T [col][k]
__device__ __align__(256) ush g_emb[BB * OUTN];                // fc output bf16

// ---- helpers ----
__device__ __forceinline__ ush f2bf(float f) {
  u32 u = __float_as_uint(f);
  u32 r = (u + 0x7FFFu + ((u >> 16) & 1u)) >> 16;   // RNE
  return (ush)r;
}
__device__ __forceinline__ float bf2f(ush u) { return __uint_as_float(((u32)u) << 16); }
__device__ __forceinline__ float sigf(float x)  { return 1.f / (1.f + __expf(-x)); }
__device__ __forceinline__ float tanhf_(float x){ float e = __expf(2.f * x); return 1.f - 2.f / (e + 1.f); }
__device__ __forceinline__ v8s ld8(const ush* p) { return *reinterpret_cast<const v8s*>(p); }
__device__ __forceinline__ int origcol(int m) { return (m & 3) * 128 + (m >> 4) * 4 + ((m >> 2) & 3); }
__device__ __forceinline__ u64 pack2f(float a, float b) {
  return (u64)__float_as_uint(a) | ((u64)__float_as_uint(b) << 32);
}
__device__ __forceinline__ void unp2f(u64 v, float& a, float& b) {
  a = __uint_as_float((u32)v); b = __uint_as_float((u32)(v >> 32));
}
__device__ __forceinline__ void ast(u64* p, u64 v) {
  __hip_atomic_store(p, v, __ATOMIC_RELAXED, __HIP_MEMORY_SCOPE_AGENT);
}
__device__ __forceinline__ u64 ald(const u64* p) {
  return __hip_atomic_load(p, __ATOMIC_RELAXED, __HIP_MEMORY_SCOPE_AGENT);
}

// two-level grid barrier: 256 blocks = 8 groups x 32; per-step-unique counters
__device__ __forceinline__ void gbar(int idx) {
  __builtin_amdgcn_s_waitcnt(0x0f70);   // vmcnt(0): drain stores
  __syncthreads();
  if (threadIdx.x == 0) {
    const int grp = blockIdx.x >> 5;
    u32 old = __hip_atomic_fetch_add(&g_barg[idx * 8 + grp], 1u, __ATOMIC_RELEASE, __HIP_MEMORY_SCOPE_AGENT);
    if (old == 31u)
      __hip_atomic_fetch_add(&g_barr[idx], 1u, __ATOMIC_RELEASE, __HIP_MEMORY_SCOPE_AGENT);
    while (__hip_atomic_load(&g_barr[idx], __ATOMIC_ACQUIRE, __HIP_MEMORY_SCOPE_AGENT) < 8u)
      __builtin_amdgcn_s_sleep(8);
  }
  __syncthreads();
}

// ---- prep kernels ----
__global__ void kzero() {
  int idx = blockIdx.x * 256 + threadIdx.x;   // grid 10
  if (idx < NBAR * 8) g_barg[idx] = 0u;
  if (idx < NBAR) g_barr[idx] = 0u;
}

__global__ void kpackx(const float* __restrict__ seq) {
  int idx = blockIdx.x * 256 + threadIdx.x;   // < TT*BB*KXP
  int kk = idx % KXP; int rest = idx / KXP;
  int b = rest % BB;  int t = rest / BB;
  float v = (kk < INN) ? seq[((size_t)b * TT + t) * INN + kk] : 0.f;
  g_xpad[idx] = f2bf(v);
}

__global__ void kpackw(const float* __restrict__ Wih0, const float* __restrict__ Whh0,
                       const float* __restrict__ Wih1, const float* __restrict__ Whh1,
                       const float* __restrict__ fcw,  const float* __restrict__ decw) {
  int idx = blockIdx.x * 256 + threadIdx.x;   // grid 10688
  if (idx < 49152) {                          // wtih0: [m][96]
    int m = idx / KXP, k = idx % KXP;
    g_wtih0[idx] = f2bf((k < INN) ? Wih0[k * 512 + origcol(m)] : 0.f);
  } else if (idx < 114688) {
    int j = idx - 49152; int m = j / HH, k = j % HH;
    g_wthh0[j] = f2bf(Whh0[k * 512 + origcol(m)]);
  } else if (idx < 180224) {
    int j = idx - 114688; int m = j / HH, k = j % HH;
    g_wtih1[j] = f2bf(Wih1[k * 512 + origcol(m)]);
  } else if (idx < 245760) {
    int j = idx - 180224; int m = j / HH, k = j % HH;
    g_wthh1[j] = f2bf(Whh1[k * 512 + origcol(m)]);
  } else if (idx < 278528) {                  // fcwt [c][128]
    int j = idx - 245760; int c = j / HH, k = j % HH;
    g_fcwt[j] = f2bf(fcw[k * OUTN + c]);
  } else {                                    // decwt [c][256], coalesced reads
    int j = idx - 278528; int n = j % DECN, k = j / DECN;
    g_decwt[(size_t)n * OUTN + k] = f2bf(decw[(size_t)k * DECN + n]);
  }
}

// G1[t][g][row][16] = BN_ih0(x_t @ Wih0) + b0 (folded), transposed-MFMA orientation.
__global__ __launch_bounds__(512) void kprep(const float* __restrict__ gih0,
                                             const float* __restrict__ bih0,
                                             const float* __restrict__ b0) {
  const int t = blockIdx.x >> 3, ct = blockIdx.x & 7;
  const int tid = threadIdx.x, wv = tid >> 6, l = tid & 63;
  const int lm = l & 15, lq = l >> 4;
  const int R0 = wv * 128;
  __shared__ float sred[8][64][2];
  __shared__ float scoef[64][2];

  v8s af[4][3];
#pragma unroll
  for (int tt = 0; tt < 4; ++tt)
#pragma unroll
    for (int ks = 0; ks < 3; ++ks)
      af[tt][ks] = ld8(&g_wtih0[(ct * 64 + tt * 16 + lm) * KXP + ks * 32 + lq * 8]);

  const v4f vz = {0.f, 0.f, 0.f, 0.f};
  v4f acc[8][4];
#pragma unroll
  for (int mt = 0; mt < 8; ++mt)
#pragma unroll
    for (int tt = 0; tt < 4; ++tt) acc[mt][tt] = vz;

#pragma unroll
  for (int mt = 0; mt < 8; ++mt) {
    const ush* xr = g_xpad + ((size_t)t * BB + R0 + mt * 16 + lm) * KXP + lq * 8;
    v8s bx0 = ld8(xr), bx1 = ld8(xr + 32), bx2 = ld8(xr + 64);
#pragma unroll
    for (int tt = 0; tt < 4; ++tt) {
      acc[mt][tt] = __builtin_amdgcn_mfma_f32_16x16x32_bf16(af[tt][0], bx0, acc[mt][tt], 0, 0, 0);
      acc[mt][tt] = __builtin_amdgcn_mfma_f32_16x16x32_bf16(af[tt][1], bx1, acc[mt][tt], 0, 0, 0);
      acc[mt][tt] = __builtin_amdgcn_mfma_f32_16x16x32_bf16(af[tt][2], bx2, acc[mt][tt], 0, 0, 0);
    }
  }
  float S[4][4], Q[4][4];
#pragma unroll
  for (int tt = 0; tt < 4; ++tt)
#pragma unroll
    for (int r = 0; r < 4; ++r) {
      float s = 0.f, q = 0.f;
#pragma unroll
      for (int mt = 0; mt < 8; ++mt) { float a = acc[mt][tt][r]; s += a; q += a * a; }
#pragma unroll
      for (int off = 1; off < 16; off <<= 1) { s += __shfl_xor(s, off); q += __shfl_xor(q, off); }
      S[tt][r] = s; Q[tt][r] = q;
    }
  if (lm == 0)
#pragma unroll
    for (int tt = 0; tt < 4; ++tt)
#pragma unroll
      for (int r = 0; r < 4; ++r) {
        sred[wv][tt * 16 + lq * 4 + r][0] = S[tt][r];
        sred[wv][tt * 16 + lq * 4 + r][1] = Q[tt][r];
      }
  __syncthreads();
  if (tid < 64) {
    float Sa = 0.f, Qa = 0.f;
#pragma unroll
    for (int w8 = 0; w8 < 8; ++w8) { Sa += sred[w8][tid][0]; Qa += sred[w8][tid][1]; }
    int oc = origcol(ct * 64 + tid);
    float m_ = Sa * (1.f / BB), v_ = Qa * (1.f / BB) - m_ * m_;
    float A = gih0[oc] * rsqrtf(v_ + EPSB);
    scoef[tid][0] = A; scoef[tid][1] = bih0[oc] - A * m_ + b0[oc];
  }
  __syncthreads();
  float CA[4][4], CD[4][4];
#pragma unroll
  for (int tt = 0; tt < 4; ++tt)
#pragma unroll
    for (int r = 0; r < 4; ++r) {
      CA[tt][r] = scoef[tt * 16 + lq * 4 + r][0];
      CD[tt][r] = scoef[tt * 16 + lq * 4 + r][1];
    }
#pragma unroll
  for (int mt = 0; mt < 8; ++mt) {
    const int row = R0 + mt * 16 + lm;
#pragma unroll
    for (int tt = 0; tt < 4; ++tt) {
      const int g = ct * 4 + tt;
      u32 lo = (u32)f2bf(CA[tt][0] * acc[mt][tt][0] + CD[tt][0])
             | ((u32)f2bf(CA[tt][1] * acc[mt][tt][1] + CD[tt][1]) << 16);
      u32 hi = (u32)f2bf(CA[tt][2] * acc[mt][tt][2] + CD[tt][2])
             | ((u32)f2bf(CA[tt][3] * acc[mt][tt][3] + CD[tt][3]) << 16);
      g_G1[(((size_t)t * 32 + g) * BB + row) * 4 + lq] = (u64)lo | ((u64)hi << 32);
    }
  }
}

// ---- persistent fused recurrence: 256 blocks x 512 thr (1 block/CU), 2 barriers/step.
// Phase A (all blocks): block (c = b&31, r8 = b>>5) GEMMs 16 cols x 128 rows, 3 streams;
//   P + stat partials -> LLC (atomic u64). Weights live in registers for all steps.
// Phase B (blocks 0..63): (L = b>>5, g = b&31) owns 4 units x all rows: BN coefs from
//   partials, pointwise in-register, block-local c-BN, packed h store. c-state in regs.
__global__ __launch_bounds__(512, 2) void krec10(
    const float* __restrict__ ghh0, const float* __restrict__ bhh0,
    const float* __restrict__ gc0,  const float* __restrict__ bc0,
    const float* __restrict__ gih1, const float* __restrict__ bih1,
    const float* __restrict__ ghh1, const float* __restrict__ bhh1,
    const float* __restrict__ b1,   const float* __restrict__ gc1,
    const float* __restrict__ bc1) {
  const int bid = blockIdx.x, tid = threadIdx.x;
  const int wv = tid >> 6, l = tid & 63;
  const int lm = l & 15, lq = l >> 4;
  const int c = bid & 31, r8 = bid >> 5;
  const int rowA = r8 * 128 + wv * 16 + lm;
  const bool bAct = (bid < 64);
  const int Lb = bid >> 5, gb = bid & 31;     // phase-B role (valid when bAct)
  const int uloc = tid & 3, rgrp = tid >> 2;  // phase-B lane mapping

  __shared__ float sredA[8][16][6];
  __shared__ u64   spst[2][16][8];
  __shared__ float scoefB[16][3];
  __shared__ float scredB[8][4][2];
  __shared__ float sccoefB[4][2];
  __shared__ float sparamB[16][5];
  __shared__ float scparamB[4][2];

  const ush* const h0r = reinterpret_cast<const ush*>(g_h0s);
  const ush* const h1r = reinterpret_cast<const ush*>(g_h1s);

  // loop-invariant weight A-frags
  v8s af0[4], af1[4], af2[4];
#pragma unroll
  for (int ks = 0; ks < 4; ++ks) {
    af0[ks] = ld8(&g_wthh0[(c * 16 + lm) * HH + ks * 32 + lq * 8]);
    af1[ks] = ld8(&g_wtih1[(c * 16 + lm) * HH + ks * 32 + lq * 8]);
    af2[ks] = ld8(&g_wthh1[(c * 16 + lm) * HH + ks * 32 + lq * 8]);
  }
  if (bAct) {
    if (tid < 16) {
      int oc = origcol(gb * 16 + tid);
      if (Lb == 0) { sparamB[tid][0] = ghh0[oc]; sparamB[tid][1] = bhh0[oc]; }
      else {
        sparamB[tid][0] = gih1[oc]; sparamB[tid][1] = bih1[oc];
        sparamB[tid][2] = ghh1[oc]; sparamB[tid][3] = bhh1[oc]; sparamB[tid][4] = b1[oc];
      }
    }
    if (tid >= 16 && tid < 20) {
      int uu = gb * 4 + (tid - 16);
      scparamB[tid - 16][0] = (Lb == 0) ? gc0[uu] : gc1[uu];
      scparamB[tid - 16][1] = (Lb == 0) ? bc0[uu] : bc1[uu];
    }
  }
  float cstB[8];
#pragma unroll
  for (int i = 0; i < 8; ++i) cstB[i] = 0.f;
  __syncthreads();

  const v4f vz = {0.f, 0.f, 0.f, 0.f};

  for (int s = 0; s <= TT; ++s) {
    // ================= PHASE A =================
    v4f P0 = vz, P1 = vz, P2 = vz;
    if (s >= 1) {
      const ush* hp = h0r + ((size_t)(s - 1) * BB + rowA) * HH + lq * 8;
#pragma unroll
      for (int ks = 0; ks < 4; ++ks) {
        v8s b = ld8(hp + ks * 32);
        P0 = __builtin_amdgcn_mfma_f32_16x16x32_bf16(af0[ks], b, P0, 0, 0, 0);
        P1 = __builtin_amdgcn_mfma_f32_16x16x32_bf16(af1[ks], b, P1, 0, 0, 0);
      }
    }
    if (s >= 2) {
      const ush* hp = h1r + ((size_t)(s - 2) * BB + rowA) * HH + lq * 8;
#pragma unroll
      for (int ks = 0; ks < 4; ++ks)
        P2 = __builtin_amdgcn_mfma_f32_16x16x32_bf16(af2[ks], ld8(hp + ks * 32), P2, 0, 0, 0);
    }
    {
      const size_t pb0 = (((size_t)0 * 32 + c) * 1024 + rowA) * 8 + lq * 2;
      const size_t pb1 = (((size_t)1 * 32 + c) * 1024 + rowA) * 8 + lq * 2;
      const size_t pb2 = (((size_t)2 * 32 + c) * 1024 + rowA) * 8 + lq * 2;
      if (s < TT) { ast(&g_Pu[pb0], pack2f(P0[0], P0[1])); ast(&g_Pu[pb0 + 1], pack2f(P0[2], P0[3])); }
      if (s >= 1) {
        ast(&g_Pu[pb1], pack2f(P1[0], P1[1])); ast(&g_Pu[pb1 + 1], pack2f(P1[2], P1[3]));
        ast(&g_Pu[pb2], pack2f(P2[0], P2[1])); ast(&g_Pu[pb2 + 1], pack2f(P2[2], P2[3]));
      }
    }
    // stat partials over this wave's 16 rows
    {
      float S[3][4], Q[3][4];
#pragma unroll
      for (int r = 0; r < 4; ++r) {
        S[0][r] = P0[r]; Q[0][r] = P0[r] * P0[r];
        S[1][r] = P1[r]; Q[1][r] = P1[r] * P1[r];
        S[2][r] = P2[r]; Q[2][r] = P2[r] * P2[r];
      }
#pragma unroll
      for (int st = 0; st < 3; ++st)
#pragma unroll
        for (int r = 0; r < 4; ++r) {
          float s_ = S[st][r], q_ = Q[st][r];
#pragma unroll
          for (int off = 1; off < 16; off <<= 1) { s_ += __shfl_xor(s_, off); q_ += __shfl_xor(q_, off); }
          S[st][r] = s_; Q[st][r] = q_;
        }
      if (lm == 0)
#pragma unroll
        for (int st = 0; st < 3; ++st)
#pragma unroll
          for (int r = 0; r < 4; ++r) {
            sredA[wv][lq * 4 + r][st * 2]     = S[st][r];
            sredA[wv][lq * 4 + r][st * 2 + 1] = Q[st][r];
          }
      __syncthreads();
      if (tid < 16) {
#pragma unroll
        for (int st = 0; st < 3; ++st) {
          float Sa = 0.f, Qa = 0.f;
#pragma unroll
          for (int w8 = 0; w8 < 8; ++w8) { Sa += sredA[w8][tid][st * 2]; Qa += sredA[w8][tid][st * 2 + 1]; }
          ast(&g_pstu[((c * 3 + st) * 16 + tid) * 8 + r8], pack2f(Sa, Qa));
        }
      }
      __syncthreads();   // protect sredA reuse next step
    }
    gbar(2 * s);

    // ================= PHASE B (64 blocks) =================
    const bool act = bAct && ((Lb == 0) ? (s < TT) : (s >= 1));
    if (act) {
      if (Lb == 0) {
        if (tid < 128) {
          int cb = tid >> 3, rr = tid & 7;
          spst[0][cb][rr] = ald(&g_pstu[((gb * 3 + 0) * 16 + cb) * 8 + rr]);
        }
      } else {
        if (tid < 256) {
          int st = (tid >> 7) + 1, j = tid & 127, cb = j >> 3, rr = j & 7;
          spst[st - 1][cb][rr] = ald(&g_pstu[((gb * 3 + st) * 16 + cb) * 8 + rr]);
        }
      }
      __syncthreads();
      if (tid < 16) {
        if (Lb == 0) {
          float S = 0.f, Q = 0.f;
#pragma unroll
          for (int rr = 0; rr < 8; ++rr) { float a, b; unp2f(spst[0][tid][rr], a, b); S += a; Q += b; }
          float m_ = S * (1.f / BB), v_ = Q * (1.f / BB) - m_ * m_;
          float Ah = sparamB[tid][0] * rsqrtf(v_ + EPSB);
          scoefB[tid][0] = Ah; scoefB[tid][1] = sparamB[tid][1] - Ah * m_; scoefB[tid][2] = 0.f;
        } else {
          float S1 = 0.f, Q1 = 0.f, S2 = 0.f, Q2 = 0.f;
#pragma unroll
          for (int rr = 0; rr < 8; ++rr) {
            float a, b; unp2f(spst[0][tid][rr], a, b); S1 += a; Q1 += b;
            unp2f(spst[1][tid][rr], a, b); S2 += a; Q2 += b;
          }
          float m1 = S1 * (1.f / BB), v1 = Q1 * (1.f / BB) - m1 * m1;
          float Ai = sparamB[tid][0] * rsqrtf(v1 + EPSB);
          float m2 = S2 * (1.f / BB), v2 = Q2 * (1.f / BB) - m2 * m2;
          float Ah = sparamB[tid][2] * rsqrtf(v2 + EPSB);
          scoefB[tid][0] = Ai; scoefB[tid][1] = Ah;
          scoefB[tid][2] = sparamB[tid][1] - Ai * m1 + sparamB[tid][3] - Ah * m2 + sparamB[tid][4];
        }
      }
      __syncthreads();
      float C0[4], C1[4], C2[4];
#pragma unroll
      for (int r = 0; r < 4; ++r) {
        C0[r] = scoefB[uloc * 4 + r][0];
        C1[r] = scoefB[uloc * 4 + r][1];
        C2[r] = scoefB[uloc * 4 + r][2];
      }
      const u64* Pa = &g_Pu[(((size_t)((Lb == 0) ? 0 : 1) * 32 + gb) * 1024) * 8];
      const u64* Pb = &g_Pu[(((size_t)2 * 32 + gb) * 1024) * 8];
      const u64* G1p = &g_G1[(((size_t)s * 32 + gb) * 1024) * 4];
      float so[8], cS = 0.f, cQ = 0.f;
#pragma unroll
      for (int i = 0; i < 8; ++i) {
        const int row = rgrp * 8 + i;
        float a0, a1, a2, a3;
        unp2f(ald(&Pa[row * 8 + uloc * 2]), a0, a1);
        unp2f(ald(&Pa[row * 8 + uloc * 2 + 1]), a2, a3);
        float gf, gi, go, gg;
        if (Lb == 0) {
          u64 g1 = G1p[row * 4 + uloc];   // plain load, per-step-unique
          gf = bf2f((ush)g1)         + C0[0] * a0 + C1[0];
          gi = bf2f((ush)(g1 >> 16)) + C0[1] * a1 + C1[1];
          go = bf2f((ush)(g1 >> 32)) + C0[2] * a2 + C1[2];
          gg = bf2f((ush)(g1 >> 48)) + C0[3] * a3 + C1[3];
        } else {
          float b0_, b1_, b2_, b3_;
          unp2f(ald(&Pb[row * 8 + uloc * 2]), b0_, b1_);
          unp2f(ald(&Pb[row * 8 + uloc * 2 + 1]), b2_, b3_);
          gf = C0[0] * a0 + C1[0] * b0_ + C2[0];
          gi = C0[1] * a1 + C1[1] * b1_ + C2[1];
          go = C0[2] * a2 + C1[2] * b2_ + C2[2];
          gg = C0[3] * a3 + C1[3] * b3_ + C2[3];
        }
        float c1 = sigf(gf) * cstB[i] + sigf(gi) * tanhf_(gg);
        cstB[i] = c1; so[i] = sigf(go);
        cS += c1; cQ += c1 * c1;
      }
      // block-local c-BN
#pragma unroll
      for (int off = 4; off < 64; off <<= 1) { cS += __shfl_xor(cS, off); cQ += __shfl_xor(cQ, off); }
      if (l < 4) { scredB[wv][l][0] = cS; scredB[wv][l][1] = cQ; }
      __syncthreads();
      if (tid < 4) {
        float S = 0.f, Q = 0.f;
#pragma unroll
        for (int w8 = 0; w8 < 8; ++w8) { S += scredB[w8][tid][0]; Q += scredB[w8][tid][1]; }
        float m_ = S * (1.f / BB), v_ = Q * (1.f / BB) - m_ * m_;
        float ac = scparamB[tid][0] * rsqrtf(v_ + EPSB);
        sccoefB[tid][0] = ac; sccoefB[tid][1] = scparamB[tid][1] - ac * m_;
      }
      __syncthreads();
      const float ac = sccoefB[uloc][0], dc = sccoefB[uloc][1];
      u64* hd = (Lb == 0) ? &g_h0s[(size_t)s * BB * 32] : &g_h1s[(size_t)(s - 1) * BB * 32];
#pragma unroll
      for (int i = 0; i < 8; ++i) {
        const int row = rgrp * 8 + i;
        u32 v = (u32)f2bf(so[i] * tanhf_(ac * cstB[i] + dc));
        u32 a = v | (__shfl_xor(v, 1) << 16);   // valid on even uloc
        u32 b = __shfl_xor(a, 2);               // uloc0 <- (u2,u3)
        if (uloc == 0) ast(&hd[(size_t)row * 32 + gb], (u64)a | ((u64)b << 32));
      }
    }
    gbar(2 * s + 1);
  }
}

// ---- epilogue: emb = h1(T-1) @ fc_w + fc_b (bf16 out) ----
__global__ __launch_bounds__(256) void kfc(const float* __restrict__ fcb) {
  const int tid = threadIdx.x, w = tid >> 6, l = tid & 63;
  const int lm = l & 15, lq = l >> 4;
  const int col = blockIdx.x * 16 + lm;   // grid 16
  const ush* hsrc = reinterpret_cast<const ush*>(g_h1s) + (size_t)(TT - 1) * BB * HH;
  v8s bf[4];
#pragma unroll
  for (int ks = 0; ks < 4; ++ks) bf[ks] = ld8(&g_fcwt[col * HH + ks * 32 + lq * 8]);
  const float bias = fcb[col];
  const v4f vz = {0.f, 0.f, 0.f, 0.f};
#pragma unroll
  for (int mt = 0; mt < 16; ++mt) {
    const int rowa = w * 256 + mt * 16 + lm;
    const ush* ap = hsrc + (size_t)rowa * HH + lq * 8;
    v4f acc = vz;
#pragma unroll
    for (int ks = 0; ks < 4; ++ks)
      acc = __builtin_amdgcn_mfma_f32_16x16x32_bf16(ld8(ap + ks * 32), bf[ks], acc, 0, 0, 0);
#pragma unroll
    for (int r = 0; r < 4; ++r) {
      int row = w * 256 + mt * 16 + lq * 4 + r;
      g_emb[row * OUTN + col] = f2bf(acc[r] + bias);
    }
  }
}

// ---- epilogue: out = emb @ dec_w + dec_b, transposed MFMA -> 16B coalesced stores ----
__global__ __launch_bounds__(256) void kdec(const float* __restrict__ decb, float* __restrict__ out) {
  const int tid = threadIdx.x, wv = tid >> 6, l = tid & 63;
  const int lm = l & 15, lq = l >> 4;
  const int c0 = blockIdx.x * 16;         // grid 600
  const int R0 = wv * 256;
  v8s af[8];
#pragma unroll
  for (int ks = 0; ks < 8; ++ks) af[ks] = ld8(&g_decwt[(size_t)(c0 + lm) * OUTN + ks * 32 + lq * 8]);
  float bias[4];
#pragma unroll
  for (int r = 0; r < 4; ++r) bias[r] = decb[c0 + lq * 4 + r];
  const v4f vz = {0.f, 0.f, 0.f, 0.f};
#pragma unroll
  for (int mt = 0; mt < 16; ++mt) {
    const int row = R0 + mt * 16 + lm;
    const ush* bp = g_emb + (size_t)row * OUTN + lq * 8;
    v4f acc = vz;
#pragma unroll
    for (int ks = 0; ks < 8; ++ks)
      acc = __builtin_amdgcn_mfma_f32_16x16x32_bf16(af[ks], ld8(bp + ks * 32), acc, 0, 0, 0);
    v4f o;
#pragma unroll
    for (int r = 0; r < 4; ++r) o[r] = acc[r] + bias[r];
    *reinterpret_cast<v4f*>(&out[(size_t)row * DECN + c0 + lq * 4]) = o;
  }
}

extern "C" void kernel_launch(void* const* d_in, const int* in_sizes, int n_in,
                              void* d_out, int out_size, void* d_ws, size_t ws_size,
                              hipStream_t stream) {
  const float* seq  = (const float*)d_in[0];
  const float* Wih0 = (const float*)d_in[1];
  const float* Whh0 = (const float*)d_in[2];
  const float* b0   = (const float*)d_in[3];
  const float* gih0 = (const float*)d_in[4];
  const float* bih0 = (const float*)d_in[5];
  const float* ghh0 = (const float*)d_in[6];
  const float* bhh0 = (const float*)d_in[7];
  const float* gc0  = (const float*)d_in[8];
  const float* bc0  = (const float*)d_in[9];
  const float* Wih1 = (const float*)d_in[10];
  const float* Whh1 = (const float*)d_in[11];
  const float* b1   = (const float*)d_in[12];
  const float* gih1 = (const float*)d_in[13];
  const float* bih1 = (const float*)d_in[14];
  const float* ghh1 = (const float*)d_in[15];
  const float* bhh1 = (const float*)d_in[16];
  const float* gc1  = (const float*)d_in[17];
  const float* bc1  = (const float*)d_in[18];
  const float* fcw  = (const float*)d_in[19];
  const float* fcb  = (const float*)d_in[20];
  const float* decw = (const float*)d_in[21];
  const float* decb = (const float*)d_in[22];
  float* out = (float*)d_out;
  (void)in_sizes; (void)n_in; (void)out_size; (void)d_ws; (void)ws_size;

  kzero<<<dim3(10), dim3(256), 0, stream>>>();
  kpackx<<<dim3((TT * BB * KXP) / 256), dim3(256), 0, stream>>>(seq);
  kpackw<<<dim3(10688), dim3(256), 0, stream>>>(Wih0, Whh0, Wih1, Whh1, fcw, decw);
  kprep<<<dim3(TT * 8), dim3(512), 0, stream>>>(gih0, bih0, b0);
  krec10<<<dim3(256), dim3(512), 0, stream>>>(ghh0, bhh0, gc0, bc0,
                                              gih1, bih1, ghh1, bhh1, b1, gc1, bc1);
  kfc<<<dim3(16), dim3(256), 0, stream>>>(fcb);
  kdec<<<dim3(600), dim3(256), 0, stream>>>(decb, out);
}